// Round 15
// baseline (120.688 us; speedup 1.0000x reference)
//
#include <hip/hip_runtime.h>
#include <math.h>

#define NCH 48
#define NB 16
#define PLANE 16384
#define NPLANES 768

// d_ws float layout
#define WS_PSUM  0
#define WS_PSQ   768
#define WS_SCALE 1536
#define WS_SHIFT 1584
#define WS_TAB   1632   // [src 4][tgt 4][6 coefs]
#define WS_CONST 1728   // [4]

typedef _Float16 h2 __attribute__((ext_vector_type(2)));

// ---------------- stage A: per-plane partial sums ----------------
__global__ __launch_bounds__(256) void stats_kernel(const float* __restrict__ x,
                                                    float* __restrict__ ws) {
  int p = blockIdx.x;
  int t = threadIdx.x;
  const float4* x4 = (const float4*)x + (size_t)p * 4096;
  float s = 0.f, q = 0.f;
  #pragma unroll
  for (int k = 0; k < 16; ++k) {
    float4 v = x4[k * 256 + t];
    s += v.x + v.y + v.z + v.w;
    q += v.x * v.x + v.y * v.y + v.z * v.z + v.w * v.w;
  }
  #pragma unroll
  for (int off = 32; off > 0; off >>= 1) {
    s += __shfl_xor(s, off, 64);
    q += __shfl_xor(q, off, 64);
  }
  __shared__ float red[8];
  int wid = t >> 6, lane = t & 63;
  if (lane == 0) { red[wid] = s; red[4 + wid] = q; }
  __syncthreads();
  if (t == 0) {
    ws[WS_PSUM + p] = red[0] + red[1] + red[2] + red[3];
    ws[WS_PSQ  + p] = red[4] + red[5] + red[6] + red[7];
  }
}

// ---------------- stage B: BN params + merged weight table ----------------
__global__ void prep_kernel(const float* __restrict__ gamma, const float* __restrict__ beta,
                            const float* __restrict__ alphas, float* __restrict__ ws) {
  int t = threadIdx.x;
  if (t < NCH) {
    float s = 0.f, q = 0.f;
    for (int b = 0; b < NB; ++b) {
      s += ws[WS_PSUM + b * NCH + t];
      q += ws[WS_PSQ  + b * NCH + t];
    }
    const float inv = 1.0f / ((float)NB * PLANE);
    float mean = s * inv;
    float var  = q * inv - mean * mean;
    float sc = gamma[t] * rsqrtf(var + 1e-5f);
    ws[WS_SCALE + t] = sc;
    ws[WS_SHIFT + t] = beta[t] - mean * sc;
  }
  if (t == 0) {
    float w[14][7];
    for (int r = 0; r < 14; ++r) {
      float m = -1e30f;
      for (int k = 0; k < 7; ++k) m = fmaxf(m, alphas[r * 7 + k]);
      float sum = 0.f;
      for (int k = 0; k < 7; ++k) { float e = expf(alphas[r * 7 + k] - m); w[r][k] = e; sum += e; }
      float is = 1.0f / sum;
      for (int k = 0; k < 7; ++k) w[r][k] *= is;
    }
    for (int i = 0; i < 96; ++i) ws[WS_TAB + i] = 0.f;
    for (int i = 0; i < 4;  ++i) ws[WS_CONST + i] = 0.f;
    const int map[14][2] = {
      {0,0},{0,0},
      {0,1},{0,1},{1,1},
      {0,2},{0,2},{1,2},{2,2},
      {0,3},{0,3},{1,3},{2,3},{3,3}
    };
    for (int r = 0; r < 14; ++r) {
      int p = map[r][0], tg = map[r][1];
      float* cf = ws + WS_TAB + (p * 4 + tg) * 6;
      cf[0] += w[r][0] - w[r][2];       // identity
      cf[1] += w[r][1] * (1.0f / 9.0f); // blur (/9 folded)
      cf[2] += w[r][3];                 // fliplr
      cf[3] += w[r][4];                 // flipud
      cf[4] += w[r][5];                 // roll(+4,+4)
      cf[5] += w[r][6];                 // rot90
      ws[WS_CONST + tg] += w[r][2];     // constant w2
    }
  }
}

// ---------------- main fused kernel ----------------
// fp16 LDS planes, split-word layout, XOR swizzle on (i>>2) (R13 verified:
// conflicts 6.1M -> 1.77M). Fused multi-target pass2 via ACC hooks; all
// accumulators live only WITHIN one chunk iteration (no cross-barrier
// persistence — the R11/R12 spill trap). 6 gathers/chunk vs R13's 10.
// R14 lesson: hook macro parameter names must not collide with register
// prefixes (param V vs registers V0..V3 broke token pasting) — params are
// now VAL, registers T/U/W.

__device__ __forceinline__ float ldshw(const h2* L, int i, int j) {
  int q = ((j >> 2) & 31) ^ (i >> 2);
  h2 p = L[(i << 6) + ((j & 2) << 4) + q];
  return (j & 1) ? (float)p.y : (float)p.x;
}

#define RDQ(L, I, B, M) {                                                      \
  int q_ = (B) ^ ((I) >> 2);                                                   \
  h2 p0_ = (L)[((I) << 6) + q_];                                               \
  h2 p1_ = (L)[((I) << 6) + 32 + q_];                                          \
  M.x = (float)p0_.x; M.y = (float)p0_.y;                                      \
  M.z = (float)p1_.x; M.w = (float)p1_.y; }

#define WRQ(L, I, B, VV) {                                                     \
  int q_ = (B) ^ ((I) >> 2);                                                   \
  h2 p0_, p1_;                                                                 \
  p0_.x = (_Float16)VV.x; p0_.y = (_Float16)VV.y;                              \
  p1_.x = (_Float16)VV.z; p1_.y = (_Float16)VV.w;                              \
  (L)[((I) << 6) + q_] = p0_;                                                  \
  (L)[((I) << 6) + 32 + q_] = p1_; }

#define HROW(h, m, lo, hi)                                                     \
  h.x = lo + m.x + m.y; h.y = m.x + m.y + m.z;                                 \
  h.z = m.y + m.z + m.w; h.w = m.z + m.w + hi;

// ACC hooks: ACC(row, comp, opIdx, value)
#define FMA4A(ACC, R, OP, M) ACC(R,x,OP,M.x) ACC(R,y,OP,M.y) ACC(R,z,OP,M.z) ACC(R,w,OP,M.w)
#define FLIPLA(ACC, R, M)    ACC(R,x,2,M.w) ACC(R,y,2,M.z) ACC(R,z,2,M.y) ACC(R,w,2,M.x)
#define BLUR4A(ACC, R, Ah, Bh, Ch)                                             \
  ACC(R,x,1,(Ah.x+Bh.x+Ch.x)) ACC(R,y,1,(Ah.y+Bh.y+Ch.y))                      \
  ACC(R,z,1,(Ah.z+Bh.z+Ch.z)) ACC(R,w,1,(Ah.w+Bh.w+Ch.w))

#define GATHER(L, OI, TYC, ACC) {                                              \
  float4 m, hA, hB, hC; float lo, hi; int ri;                                  \
  ri = ((OI) == 0) ? 1 : (OI) - 1;                                             \
  RDQ(L, ri, tx, m) lo = ldshw(L, ri, cLo); hi = ldshw(L, ri, cHi);            \
  HROW(hA, m, lo, hi)                                                          \
  RDQ(L, (OI), tx, m) lo = ldshw(L, (OI), cLo); hi = ldshw(L, (OI), cHi);      \
  FMA4A(ACC, 0, 0, m)                                                          \
  HROW(hB, m, lo, hi)                                                          \
  RDQ(L, (OI)+1, tx, m) lo = ldshw(L, (OI)+1, cLo); hi = ldshw(L, (OI)+1, cHi);\
  FMA4A(ACC, 1, 0, m)                                                          \
  HROW(hC, m, lo, hi)                                                          \
  BLUR4A(ACC, 0, hA, hB, hC)                                                   \
  RDQ(L, (OI)+2, tx, m) lo = ldshw(L, (OI)+2, cLo); hi = ldshw(L, (OI)+2, cHi);\
  FMA4A(ACC, 2, 0, m)                                                          \
  HROW(hA, m, lo, hi)                                                          \
  BLUR4A(ACC, 1, hB, hC, hA)                                                   \
  RDQ(L, (OI)+3, tx, m) lo = ldshw(L, (OI)+3, cLo); hi = ldshw(L, (OI)+3, cHi);\
  FMA4A(ACC, 3, 0, m)                                                          \
  HROW(hB, m, lo, hi)                                                          \
  BLUR4A(ACC, 2, hC, hA, hB)                                                   \
  ri = ((OI) == 124) ? 126 : (OI) + 4;                                         \
  RDQ(L, ri, tx, m) lo = ldshw(L, ri, cLo); hi = ldshw(L, ri, cHi);            \
  HROW(hC, m, lo, hi)                                                          \
  BLUR4A(ACC, 3, hA, hB, hC)                                                   \
  /* fliplr */                                                                 \
  RDQ(L, (OI),   31 - tx, m) FLIPLA(ACC, 0, m)                                 \
  RDQ(L, (OI)+1, 31 - tx, m) FLIPLA(ACC, 1, m)                                 \
  RDQ(L, (OI)+2, 31 - tx, m) FLIPLA(ACC, 2, m)                                 \
  RDQ(L, (OI)+3, 31 - tx, m) FLIPLA(ACC, 3, m)                                 \
  /* flipud */                                                                 \
  RDQ(L, 127 - (OI), tx, m) FMA4A(ACC, 0, 3, m)                                \
  RDQ(L, 126 - (OI), tx, m) FMA4A(ACC, 1, 3, m)                                \
  RDQ(L, 125 - (OI), tx, m) FMA4A(ACC, 2, 3, m)                                \
  RDQ(L, 124 - (OI), tx, m) FMA4A(ACC, 3, 3, m)                                \
  /* roll(+4,+4) */                                                            \
  RDQ(L, ((OI) - 4) & 127, rc, m) FMA4A(ACC, 0, 4, m)                          \
  RDQ(L, ((OI) - 3) & 127, rc, m) FMA4A(ACC, 1, 4, m)                          \
  RDQ(L, ((OI) - 2) & 127, rc, m) FMA4A(ACC, 2, 4, m)                          \
  RDQ(L, ((OI) - 1) & 127, rc, m) FMA4A(ACC, 3, 4, m)                          \
  /* rot90 k=1: out[i][j] = src[j][127-i] */                                   \
  RDQ(L, oj,     31 - (TYC), m)                                                \
  ACC(0,x,5,m.w) ACC(1,x,5,m.z) ACC(2,x,5,m.y) ACC(3,x,5,m.x)                  \
  RDQ(L, oj + 1, 31 - (TYC), m)                                                \
  ACC(0,y,5,m.w) ACC(1,y,5,m.z) ACC(2,y,5,m.y) ACC(3,y,5,m.x)                  \
  RDQ(L, oj + 2, 31 - (TYC), m)                                                \
  ACC(0,z,5,m.w) ACC(1,z,5,m.z) ACC(2,z,5,m.y) ACC(3,z,5,m.x)                  \
  RDQ(L, oj + 3, 31 - (TYC), m)                                                \
  ACC(0,w,5,m.w) ACC(1,w,5,m.z) ACC(2,w,5,m.y) ACC(3,w,5,m.x)                  \
}

// accumulator hooks (param VAL — must not collide with register prefixes T/U/W)
#define ACC_T(R,Cc,OP,VAL)  T##R.Cc += cA##OP * (VAL);
#define ACC_TB(R,Cc,OP,VAL) T##R.Cc += cB##OP * (VAL);
#define ACC_3A(R,Cc,OP,VAL) { float v_=(VAL); T##R.Cc += cA##OP*v_; U##R.Cc += cB##OP*v_; W##R.Cc += cC##OP*v_; }
#define ACC_3B(R,Cc,OP,VAL) { float v_=(VAL); T##R.Cc += cD##OP*v_; U##R.Cc += cE##OP*v_; W##R.Cc += cF##OP*v_; }

#define LDCFS(PRE, P, TG) {                                                    \
  const float* cfp_ = wsf + WS_TAB + ((P) * 4 + (TG)) * 6;                     \
  PRE##0 = cfp_[0]; PRE##1 = cfp_[1]; PRE##2 = cfp_[2];                        \
  PRE##3 = cfp_[3]; PRE##4 = cfp_[4]; PRE##5 = cfp_[5]; }

#define SET4(A, VV) { A##0 = VV; A##1 = VV; A##2 = VV; A##3 = VV; }

#define STAGE_BN(L, OI) {                                                      \
  float4 v;                                                                    \
  v = x4[((OI)+0)*32 + tx]; v.x = v.x*sc+sh; v.y = v.y*sc+sh; v.z = v.z*sc+sh; \
  v.w = v.w*sc+sh; WRQ(L, (OI)+0, tx, v)                                       \
  v = x4[((OI)+1)*32 + tx]; v.x = v.x*sc+sh; v.y = v.y*sc+sh; v.z = v.z*sc+sh; \
  v.w = v.w*sc+sh; WRQ(L, (OI)+1, tx, v)                                       \
  v = x4[((OI)+2)*32 + tx]; v.x = v.x*sc+sh; v.y = v.y*sc+sh; v.z = v.z*sc+sh; \
  v.w = v.w*sc+sh; WRQ(L, (OI)+2, tx, v)                                       \
  v = x4[((OI)+3)*32 + tx]; v.x = v.x*sc+sh; v.y = v.y*sc+sh; v.z = v.z*sc+sh; \
  v.w = v.w*sc+sh; WRQ(L, (OI)+3, tx, v) }

#define STAGE_OUT(L, TG, OI) {                                                 \
  float4 v;                                                                    \
  v = out4[(pbase + (TG)*NCH)*4096 + ((OI)+0)*32 + tx]; WRQ(L, (OI)+0, tx, v)  \
  v = out4[(pbase + (TG)*NCH)*4096 + ((OI)+1)*32 + tx]; WRQ(L, (OI)+1, tx, v)  \
  v = out4[(pbase + (TG)*NCH)*4096 + ((OI)+2)*32 + tx]; WRQ(L, (OI)+2, tx, v)  \
  v = out4[(pbase + (TG)*NCH)*4096 + ((OI)+3)*32 + tx]; WRQ(L, (OI)+3, tx, v) }

#define WRITE4(A, TG, OI) {                                                    \
  out4[(pbase + (TG)*NCH)*4096 + ((OI)+0)*32 + tx] = A##0;                     \
  out4[(pbase + (TG)*NCH)*4096 + ((OI)+1)*32 + tx] = A##1;                     \
  out4[(pbase + (TG)*NCH)*4096 + ((OI)+2)*32 + tx] = A##2;                     \
  out4[(pbase + (TG)*NCH)*4096 + ((OI)+3)*32 + tx] = A##3; }

#define LOAD4(A, TG, OI) {                                                     \
  A##0 = out4[(pbase + (TG)*NCH)*4096 + ((OI)+0)*32 + tx];                     \
  A##1 = out4[(pbase + (TG)*NCH)*4096 + ((OI)+1)*32 + tx];                     \
  A##2 = out4[(pbase + (TG)*NCH)*4096 + ((OI)+2)*32 + tx];                     \
  A##3 = out4[(pbase + (TG)*NCH)*4096 + ((OI)+3)*32 + tx]; }

#define STASH4(A, L, OI) {                                                     \
  WRQ(L, (OI)+0, tx, A##0) WRQ(L, (OI)+1, tx, A##1)                            \
  WRQ(L, (OI)+2, tx, A##2) WRQ(L, (OI)+3, tx, A##3) }

__global__ __launch_bounds__(256, 1)
void main_kernel(const float* __restrict__ x,
                 const float* __restrict__ wsf, float* out)
{
  __shared__ h2 lds[2 * 8192];            // 64 KB total -> 2 blocks/CU
  h2* h0 = lds;
  h2* h1 = lds + 8192;
  int bx = blockIdx.x;
  int b = bx / NCH, c = bx % NCH;
  int tid = threadIdx.x;
  int ty = tid >> 5, tx = tid & 31;       // ty in 0..7
  int oj = tx << 2;
  int cLo = (tx == 0)  ? 1   : oj - 1;
  int cHi = (tx == 31) ? 126 : oj + 4;
  int rc  = (tx + 31) & 31;
  float4* out4 = (float4*)out;
  const size_t pbase = (size_t)b * 192 + c;
  const float4* x4 = (const float4*)x + (size_t)bx * 4096;
  float sc = wsf[WS_SCALE + c], sh = wsf[WS_SHIFT + c];

  float4 T0, T1, T2, T3, U0, U1, U2, U3, W0, W1, W2, W3;
  float cA0, cA1, cA2, cA3, cA4, cA5;
  float cB0, cB1, cB2, cB3, cB4, cB5;
  float cC0, cC1, cC2, cC3, cC4, cC5;
  float cD0, cD1, cD2, cD3, cD4, cD5;
  float cE0, cE1, cE2, cE3, cE4, cE5;
  float cF0, cF1, cF2, cF3, cF4, cF5;

  // stage s -> buf0
  #pragma unroll 1
  for (int k = 0; k < 4; ++k) {
    int oi = (ty + 8 * k) << 2;
    STAGE_BN(h0, oi);
  }
  __syncthreads();

  // ---- pass1: s2 = c0 + L(0,0)[s]; stash s2 -> buf1 ----
  LDCFS(cA, 0, 0)
  {
    float k0 = wsf[WS_CONST + 0];
    float4 v0; v0.x = k0; v0.y = k0; v0.z = k0; v0.w = k0;
    #pragma unroll 1
    for (int k = 0; k < 4; ++k) {
      int oi = (ty + 8 * k) << 2; int tyc = ty + 8 * k;
      SET4(T, v0)
      GATHER(h0, oi, tyc, ACC_T);
      WRITE4(T, 0, oi)
      STASH4(T, h1, oi)
    }
  }
  __syncthreads();

  // ---- pass2 (fused): gather s once, s2 once; feed T=s3, U=s4p, W=s5p ----
  LDCFS(cA, 0, 1) LDCFS(cB, 0, 2) LDCFS(cC, 0, 3)
  LDCFS(cD, 1, 1) LDCFS(cE, 1, 2) LDCFS(cF, 1, 3)
  {
    float k1 = wsf[WS_CONST + 1], k2 = wsf[WS_CONST + 2], k3 = wsf[WS_CONST + 3];
    float4 v1; v1.x = k1; v1.y = k1; v1.z = k1; v1.w = k1;
    float4 v2; v2.x = k2; v2.y = k2; v2.z = k2; v2.w = k2;
    float4 v3; v3.x = k3; v3.y = k3; v3.z = k3; v3.w = k3;
    #pragma unroll 1
    for (int k = 0; k < 4; ++k) {
      int oi = (ty + 8 * k) << 2; int tyc = ty + 8 * k;
      SET4(T, v1) SET4(U, v2) SET4(W, v3)
      GATHER(h0, oi, tyc, ACC_3A);          // s   -> (0,1),(0,2),(0,3)
      GATHER(h1, oi, tyc, ACC_3B);          // s2  -> (1,1),(1,2),(1,3)
      WRITE4(T, 1, oi)                      // s3 final
      WRITE4(U, 2, oi)                      // s4 partial
      WRITE4(W, 3, oi)                      // s5 partial
    }
  }
  __syncthreads();                          // h0 reads done; s3 visible

  // restage s3 -> buf0 (same-thread re-read, L2-hot)
  #pragma unroll 1
  for (int k = 0; k < 4; ++k) {
    int oi = (ty + 8 * k) << 2;
    STAGE_OUT(h0, 1, oi);
  }
  __syncthreads();

  // ---- pass3: s4 final (+= L(2,2)[s3]); stash s4 -> buf1 ----
  LDCFS(cA, 2, 2)
  #pragma unroll 1
  for (int k = 0; k < 4; ++k) {
    int oi = (ty + 8 * k) << 2; int tyc = ty + 8 * k;
    LOAD4(T, 2, oi)
    GATHER(h0, oi, tyc, ACC_T);
    WRITE4(T, 2, oi)
    STASH4(T, h1, oi)
  }
  __syncthreads();                          // s4 fully staged in buf1

  // ---- pass4: s5 final (+= L(2,3)[s3] + L(3,3)[s4]) ----
  LDCFS(cA, 2, 3) LDCFS(cB, 3, 3)
  #pragma unroll 1
  for (int k = 0; k < 4; ++k) {
    int oi = (ty + 8 * k) << 2; int tyc = ty + 8 * k;
    LOAD4(T, 3, oi)
    GATHER(h0, oi, tyc, ACC_T);             // s3 contribution
    GATHER(h1, oi, tyc, ACC_TB);            // s4 contribution
    WRITE4(T, 3, oi)
  }
}

extern "C" void kernel_launch(void* const* d_in, const int* in_sizes, int n_in,
                              void* d_out, int out_size, void* d_ws, size_t ws_size,
                              hipStream_t stream) {
  (void)in_sizes; (void)n_in; (void)out_size; (void)ws_size;
  const float* x     = (const float*)d_in[0];
  const float* gamma = (const float*)d_in[1];
  const float* beta  = (const float*)d_in[2];
  const float* a_red = (const float*)d_in[4];   // reference uses alphas_reduce
  float* ws  = (float*)d_ws;
  float* out = (float*)d_out;

  stats_kernel<<<NPLANES, 256, 0, stream>>>(x, ws);
  prep_kernel<<<1, 64, 0, stream>>>(gamma, beta, a_red, ws);
  main_kernel<<<NPLANES, 256, 0, stream>>>(x, ws, out);
}

// Round 16
// 117.718 us; speedup vs baseline: 1.0252x; 1.0252x over previous
//
#include <hip/hip_runtime.h>
#include <math.h>

#define NCH 48
#define NB 16
#define PLANE 16384
#define NPLANES 768

// d_ws float layout
#define WS_PSUM  0
#define WS_PSQ   768
#define WS_SCALE 1536
#define WS_SHIFT 1584
#define WS_TAB   1632   // [src 4][tgt 4][6 coefs]
#define WS_CONST 1728   // [4]

typedef _Float16 h2 __attribute__((ext_vector_type(2)));
typedef _Float16 h4 __attribute__((ext_vector_type(4)));

// ---------------- stage A: per-plane partial sums ----------------
__global__ __launch_bounds__(256) void stats_kernel(const float* __restrict__ x,
                                                    float* __restrict__ ws) {
  int p = blockIdx.x;
  int t = threadIdx.x;
  const float4* x4 = (const float4*)x + (size_t)p * 4096;
  float s = 0.f, q = 0.f;
  #pragma unroll
  for (int k = 0; k < 16; ++k) {
    float4 v = x4[k * 256 + t];
    s += v.x + v.y + v.z + v.w;
    q += v.x * v.x + v.y * v.y + v.z * v.z + v.w * v.w;
  }
  #pragma unroll
  for (int off = 32; off > 0; off >>= 1) {
    s += __shfl_xor(s, off, 64);
    q += __shfl_xor(q, off, 64);
  }
  __shared__ float red[8];
  int wid = t >> 6, lane = t & 63;
  if (lane == 0) { red[wid] = s; red[4 + wid] = q; }
  __syncthreads();
  if (t == 0) {
    ws[WS_PSUM + p] = red[0] + red[1] + red[2] + red[3];
    ws[WS_PSQ  + p] = red[4] + red[5] + red[6] + red[7];
  }
}

// ---------------- stage B: BN params + merged weight table ----------------
__global__ void prep_kernel(const float* __restrict__ gamma, const float* __restrict__ beta,
                            const float* __restrict__ alphas, float* __restrict__ ws) {
  int t = threadIdx.x;
  if (t < NCH) {
    float s = 0.f, q = 0.f;
    for (int b = 0; b < NB; ++b) {
      s += ws[WS_PSUM + b * NCH + t];
      q += ws[WS_PSQ  + b * NCH + t];
    }
    const float inv = 1.0f / ((float)NB * PLANE);
    float mean = s * inv;
    float var  = q * inv - mean * mean;
    float sc = gamma[t] * rsqrtf(var + 1e-5f);
    ws[WS_SCALE + t] = sc;
    ws[WS_SHIFT + t] = beta[t] - mean * sc;
  }
  if (t == 0) {
    float w[14][7];
    for (int r = 0; r < 14; ++r) {
      float m = -1e30f;
      for (int k = 0; k < 7; ++k) m = fmaxf(m, alphas[r * 7 + k]);
      float sum = 0.f;
      for (int k = 0; k < 7; ++k) { float e = expf(alphas[r * 7 + k] - m); w[r][k] = e; sum += e; }
      float is = 1.0f / sum;
      for (int k = 0; k < 7; ++k) w[r][k] *= is;
    }
    for (int i = 0; i < 96; ++i) ws[WS_TAB + i] = 0.f;
    for (int i = 0; i < 4;  ++i) ws[WS_CONST + i] = 0.f;
    const int map[14][2] = {
      {0,0},{0,0},
      {0,1},{0,1},{1,1},
      {0,2},{0,2},{1,2},{2,2},
      {0,3},{0,3},{1,3},{2,3},{3,3}
    };
    for (int r = 0; r < 14; ++r) {
      int p = map[r][0], tg = map[r][1];
      float* cf = ws + WS_TAB + (p * 4 + tg) * 6;
      cf[0] += w[r][0] - w[r][2];       // identity
      cf[1] += w[r][1] * (1.0f / 9.0f); // blur (/9 folded)
      cf[2] += w[r][3];                 // fliplr
      cf[3] += w[r][4];                 // flipud
      cf[4] += w[r][5];                 // roll(+4,+4)
      cf[5] += w[r][6];                 // rot90
      ws[WS_CONST + tg] += w[r][2];     // constant w2
    }
  }
}

// ---------------- main fused kernel ----------------
// R13 schedule (best measured: 111us main, VGPR 132, no spill) with
// ADJACENT-WORD quads + (i>>2) XOR swizzle: quad = one aligned 8B h4 ->
// single ds_read_b64/ds_write_b64 (R13's split-word needed 2x b32, words
// 128B apart). Bank math: byte = i*256 + (q^(i>>2))*8 -> banks {2m,2m+1};
// row reads (q=tx varies) and rot90 reads (rows 4tx+rb, i*64 === 0 mod 32)
// both give 2 lanes/bank = free (m136). R11's conflict was the i&31
// swizzle, not adjacency.

__device__ __forceinline__ float ldshw(const h2* L, int i, int j) {
  int s = ((j >> 2) & 31) ^ (i >> 2);
  h2 p = L[(i << 6) + (s << 1) + ((j & 2) >> 1)];
  return (j & 1) ? (float)p.y : (float)p.x;
}

#define RDQ(L, I, B, M) {                                                      \
  int s_ = (B) ^ ((I) >> 2);                                                   \
  h4 pp_ = *(const h4*)((L) + (((I) << 6) + (s_ << 1)));                       \
  M.x = (float)pp_.x; M.y = (float)pp_.y;                                      \
  M.z = (float)pp_.z; M.w = (float)pp_.w; }

#define WRQ(L, I, B, VV) {                                                     \
  int s_ = (B) ^ ((I) >> 2);                                                   \
  h4 pp_;                                                                      \
  pp_.x = (_Float16)VV.x; pp_.y = (_Float16)VV.y;                              \
  pp_.z = (_Float16)VV.z; pp_.w = (_Float16)VV.w;                              \
  *(h4*)((L) + (((I) << 6) + (s_ << 1))) = pp_; }

#define HROW(h, m, lo, hi)                                                     \
  h.x = lo + m.x + m.y; h.y = m.x + m.y + m.z;                                 \
  h.z = m.y + m.z + m.w; h.w = m.z + m.w + hi;

#define FMA4(T, C, M)                                                          \
  T.x += (C) * M.x; T.y += (C) * M.y; T.z += (C) * M.z; T.w += (C) * M.w;

#define BLUR4(T, A, B, Cq)                                                     \
  T.x += c1 * (A.x + B.x + Cq.x); T.y += c1 * (A.y + B.y + Cq.y);              \
  T.z += c1 * (A.z + B.z + Cq.z); T.w += c1 * (A.w + B.w + Cq.w);

#define FLIPL(T, M)                                                            \
  T.x += c2 * M.w; T.y += c2 * M.z; T.z += c2 * M.y; T.w += c2 * M.x;

#define GATHER(L, OI, TYC) {                                                   \
  float4 m, hA, hB, hC; float lo, hi; int ri;                                  \
  ri = ((OI) == 0) ? 1 : (OI) - 1;                                             \
  RDQ(L, ri, tx, m) lo = ldshw(L, ri, cLo); hi = ldshw(L, ri, cHi);            \
  HROW(hA, m, lo, hi)                                                          \
  RDQ(L, (OI), tx, m) lo = ldshw(L, (OI), cLo); hi = ldshw(L, (OI), cHi);      \
  FMA4(T0, c0, m)                                                              \
  HROW(hB, m, lo, hi)                                                          \
  RDQ(L, (OI)+1, tx, m) lo = ldshw(L, (OI)+1, cLo); hi = ldshw(L, (OI)+1, cHi);\
  FMA4(T1, c0, m)                                                              \
  HROW(hC, m, lo, hi)                                                          \
  BLUR4(T0, hA, hB, hC)                                                        \
  RDQ(L, (OI)+2, tx, m) lo = ldshw(L, (OI)+2, cLo); hi = ldshw(L, (OI)+2, cHi);\
  FMA4(T2, c0, m)                                                              \
  HROW(hA, m, lo, hi)                                                          \
  BLUR4(T1, hB, hC, hA)                                                        \
  RDQ(L, (OI)+3, tx, m) lo = ldshw(L, (OI)+3, cLo); hi = ldshw(L, (OI)+3, cHi);\
  FMA4(T3, c0, m)                                                              \
  HROW(hB, m, lo, hi)                                                          \
  BLUR4(T2, hC, hA, hB)                                                        \
  ri = ((OI) == 124) ? 126 : (OI) + 4;                                         \
  RDQ(L, ri, tx, m) lo = ldshw(L, ri, cLo); hi = ldshw(L, ri, cHi);            \
  HROW(hC, m, lo, hi)                                                          \
  BLUR4(T3, hA, hB, hC)                                                        \
  /* fliplr */                                                                 \
  RDQ(L, (OI),   31 - tx, m) FLIPL(T0, m)                                      \
  RDQ(L, (OI)+1, 31 - tx, m) FLIPL(T1, m)                                      \
  RDQ(L, (OI)+2, 31 - tx, m) FLIPL(T2, m)                                      \
  RDQ(L, (OI)+3, 31 - tx, m) FLIPL(T3, m)                                      \
  /* flipud */                                                                 \
  RDQ(L, 127 - (OI), tx, m) FMA4(T0, c3, m)                                    \
  RDQ(L, 126 - (OI), tx, m) FMA4(T1, c3, m)                                    \
  RDQ(L, 125 - (OI), tx, m) FMA4(T2, c3, m)                                    \
  RDQ(L, 124 - (OI), tx, m) FMA4(T3, c3, m)                                    \
  /* roll(+4,+4) */                                                            \
  RDQ(L, ((OI) - 4) & 127, rc, m) FMA4(T0, c4, m)                              \
  RDQ(L, ((OI) - 3) & 127, rc, m) FMA4(T1, c4, m)                              \
  RDQ(L, ((OI) - 2) & 127, rc, m) FMA4(T2, c4, m)                              \
  RDQ(L, ((OI) - 1) & 127, rc, m) FMA4(T3, c4, m)                              \
  /* rot90 k=1: out[i][j] = src[j][127-i] */                                   \
  RDQ(L, oj,     31 - (TYC), m)                                                \
  T0.x += c5 * m.w; T1.x += c5 * m.z; T2.x += c5 * m.y; T3.x += c5 * m.x;      \
  RDQ(L, oj + 1, 31 - (TYC), m)                                                \
  T0.y += c5 * m.w; T1.y += c5 * m.z; T2.y += c5 * m.y; T3.y += c5 * m.x;      \
  RDQ(L, oj + 2, 31 - (TYC), m)                                                \
  T0.z += c5 * m.w; T1.z += c5 * m.z; T2.z += c5 * m.y; T3.z += c5 * m.x;      \
  RDQ(L, oj + 3, 31 - (TYC), m)                                                \
  T0.w += c5 * m.w; T1.w += c5 * m.z; T2.w += c5 * m.y; T3.w += c5 * m.x;      \
}

#define LDCF(P, TG) {                                                          \
  const float* cfp = wsf + WS_TAB + ((P) * 4 + (TG)) * 6;                      \
  c0 = cfp[0]; c1 = cfp[1]; c2 = cfp[2]; c3 = cfp[3]; c4 = cfp[4]; c5 = cfp[5]; }

#define SETC(K) {                                                              \
  float cst = wsf[WS_CONST + (K)];                                             \
  T0.x = cst; T0.y = cst; T0.z = cst; T0.w = cst; T1 = T0; T2 = T0; T3 = T0; }

#define STAGE_BN(L, OI) {                                                      \
  float4 v;                                                                    \
  v = x4[((OI)+0)*32 + tx]; v.x = v.x*sc+sh; v.y = v.y*sc+sh; v.z = v.z*sc+sh; \
  v.w = v.w*sc+sh; WRQ(L, (OI)+0, tx, v)                                       \
  v = x4[((OI)+1)*32 + tx]; v.x = v.x*sc+sh; v.y = v.y*sc+sh; v.z = v.z*sc+sh; \
  v.w = v.w*sc+sh; WRQ(L, (OI)+1, tx, v)                                       \
  v = x4[((OI)+2)*32 + tx]; v.x = v.x*sc+sh; v.y = v.y*sc+sh; v.z = v.z*sc+sh; \
  v.w = v.w*sc+sh; WRQ(L, (OI)+2, tx, v)                                       \
  v = x4[((OI)+3)*32 + tx]; v.x = v.x*sc+sh; v.y = v.y*sc+sh; v.z = v.z*sc+sh; \
  v.w = v.w*sc+sh; WRQ(L, (OI)+3, tx, v) }

#define STAGE_OUT(L, TG, OI) {                                                 \
  float4 v;                                                                    \
  v = out4[(pbase + (TG)*NCH)*4096 + ((OI)+0)*32 + tx]; WRQ(L, (OI)+0, tx, v)  \
  v = out4[(pbase + (TG)*NCH)*4096 + ((OI)+1)*32 + tx]; WRQ(L, (OI)+1, tx, v)  \
  v = out4[(pbase + (TG)*NCH)*4096 + ((OI)+2)*32 + tx]; WRQ(L, (OI)+2, tx, v)  \
  v = out4[(pbase + (TG)*NCH)*4096 + ((OI)+3)*32 + tx]; WRQ(L, (OI)+3, tx, v) }

#define WRITEV(TG, OI) {                                                       \
  out4[(pbase + (TG)*NCH)*4096 + ((OI)+0)*32 + tx] = T0;                       \
  out4[(pbase + (TG)*NCH)*4096 + ((OI)+1)*32 + tx] = T1;                       \
  out4[(pbase + (TG)*NCH)*4096 + ((OI)+2)*32 + tx] = T2;                       \
  out4[(pbase + (TG)*NCH)*4096 + ((OI)+3)*32 + tx] = T3; }

#define LOADV(TG, OI) {                                                        \
  T0 = out4[(pbase + (TG)*NCH)*4096 + ((OI)+0)*32 + tx];                       \
  T1 = out4[(pbase + (TG)*NCH)*4096 + ((OI)+1)*32 + tx];                       \
  T2 = out4[(pbase + (TG)*NCH)*4096 + ((OI)+2)*32 + tx];                       \
  T3 = out4[(pbase + (TG)*NCH)*4096 + ((OI)+3)*32 + tx]; }

#define STASHV(L, OI) {                                                        \
  WRQ(L, (OI)+0, tx, T0) WRQ(L, (OI)+1, tx, T1)                                \
  WRQ(L, (OI)+2, tx, T2) WRQ(L, (OI)+3, tx, T3) }

__global__ __launch_bounds__(256, 1)
void main_kernel(const float* __restrict__ x,
                 const float* __restrict__ wsf, float* out)
{
  __shared__ h2 lds[2 * 8192];            // 64 KB total -> 2 blocks/CU
  h2* h0 = lds;
  h2* h1 = lds + 8192;
  int bx = blockIdx.x;
  int b = bx / NCH, c = bx % NCH;
  int tid = threadIdx.x;
  int ty = tid >> 5, tx = tid & 31;       // ty in 0..7
  int oj = tx << 2;
  int cLo = (tx == 0)  ? 1   : oj - 1;
  int cHi = (tx == 31) ? 126 : oj + 4;
  int rc  = (tx + 31) & 31;
  float4* out4 = (float4*)out;
  const size_t pbase = (size_t)b * 192 + c;
  const float4* x4 = (const float4*)x + (size_t)bx * 4096;
  float sc = wsf[WS_SCALE + c], sh = wsf[WS_SHIFT + c];

  float4 T0, T1, T2, T3;
  float c0, c1, c2, c3, c4, c5;

  // stage s -> buf0
  #pragma unroll 1
  for (int k = 0; k < 4; ++k) {
    int oi = (ty + 8 * k) << 2;
    STAGE_BN(h0, oi);
  }
  __syncthreads();

  // s2 = L(0,0)[s]; stash s2 -> buf1
  #pragma unroll 1
  for (int k = 0; k < 4; ++k) {
    int oi = (ty + 8 * k) << 2; int tyc = ty + 8 * k;
    SETC(0); LDCF(0, 0);
    GATHER(h0, oi, tyc);
    WRITEV(0, oi);
    STASHV(h1, oi);
  }
  __syncthreads();

  // s3 full; s4,s5 partial contributions from s and s2
  #pragma unroll 1
  for (int k = 0; k < 4; ++k) {
    int oi = (ty + 8 * k) << 2; int tyc = ty + 8 * k;
    SETC(1); LDCF(0, 1); GATHER(h0, oi, tyc);
             LDCF(1, 1); GATHER(h1, oi, tyc);
    WRITEV(1, oi);
    SETC(2); LDCF(0, 2); GATHER(h0, oi, tyc);
             LDCF(1, 2); GATHER(h1, oi, tyc);
    WRITEV(2, oi);                          // partial s4
    SETC(3); LDCF(0, 3); GATHER(h0, oi, tyc);
             LDCF(1, 3); GATHER(h1, oi, tyc);
    WRITEV(3, oi);                          // partial s5
  }
  __syncthreads();                          // all buf0 reads done; s3 visible

  // restage s3 -> buf0
  #pragma unroll 1
  for (int k = 0; k < 4; ++k) {
    int oi = (ty + 8 * k) << 2;
    STAGE_OUT(h0, 1, oi);
  }
  __syncthreads();

  // s4 final (+= L(2,2)[s3]); stash s4 -> buf1 from regs (s2 reads all done)
  #pragma unroll 1
  for (int k = 0; k < 4; ++k) {
    int oi = (ty + 8 * k) << 2; int tyc = ty + 8 * k;
    LOADV(2, oi); LDCF(2, 2); GATHER(h0, oi, tyc); WRITEV(2, oi);
    STASHV(h1, oi);
  }
  __syncthreads();                          // s4 fully staged in buf1

  // s5 final: one RMW round, both remaining sources resident in LDS
  // (s3 in buf0, s4 in buf1)
  #pragma unroll 1
  for (int k = 0; k < 4; ++k) {
    int oi = (ty + 8 * k) << 2; int tyc = ty + 8 * k;
    LOADV(3, oi);
    LDCF(2, 3); GATHER(h0, oi, tyc);
    LDCF(3, 3); GATHER(h1, oi, tyc);
    WRITEV(3, oi);
  }
}

extern "C" void kernel_launch(void* const* d_in, const int* in_sizes, int n_in,
                              void* d_out, int out_size, void* d_ws, size_t ws_size,
                              hipStream_t stream) {
  (void)in_sizes; (void)n_in; (void)out_size; (void)ws_size;
  const float* x     = (const float*)d_in[0];
  const float* gamma = (const float*)d_in[1];
  const float* beta  = (const float*)d_in[2];
  const float* a_red = (const float*)d_in[4];   // reference uses alphas_reduce
  float* ws  = (float*)d_ws;
  float* out = (float*)d_out;

  stats_kernel<<<NPLANES, 256, 0, stream>>>(x, ws);
  prep_kernel<<<1, 64, 0, stream>>>(gamma, beta, a_red, ws);
  main_kernel<<<NPLANES, 256, 0, stream>>>(x, ws, out);
}

// Round 18
// 113.414 us; speedup vs baseline: 1.0641x; 1.0379x over previous
//
#include <hip/hip_runtime.h>
#include <math.h>

#define NCH 48
#define NB 16
#define PLANE 16384
#define NPLANES 768

// d_ws float layout
#define WS_PSUM  0
#define WS_PSQ   768
#define WS_SCALE 1536
#define WS_SHIFT 1584
#define WS_TAB   1632   // [src 4][tgt 4][6 coefs]
#define WS_CONST 1728   // [4]

typedef _Float16 h2 __attribute__((ext_vector_type(2)));
typedef _Float16 h4 __attribute__((ext_vector_type(4)));

// ---------------- stage A: per-plane partial sums ----------------
__global__ __launch_bounds__(256) void stats_kernel(const float* __restrict__ x,
                                                    float* __restrict__ ws) {
  int p = blockIdx.x;
  int t = threadIdx.x;
  const float4* x4 = (const float4*)x + (size_t)p * 4096;
  float s = 0.f, q = 0.f;
  #pragma unroll
  for (int k = 0; k < 16; ++k) {
    float4 v = x4[k * 256 + t];
    s += v.x + v.y + v.z + v.w;
    q += v.x * v.x + v.y * v.y + v.z * v.z + v.w * v.w;
  }
  #pragma unroll
  for (int off = 32; off > 0; off >>= 1) {
    s += __shfl_xor(s, off, 64);
    q += __shfl_xor(q, off, 64);
  }
  __shared__ float red[8];
  int wid = t >> 6, lane = t & 63;
  if (lane == 0) { red[wid] = s; red[4 + wid] = q; }
  __syncthreads();
  if (t == 0) {
    ws[WS_PSUM + p] = red[0] + red[1] + red[2] + red[3];
    ws[WS_PSQ  + p] = red[4] + red[5] + red[6] + red[7];
  }
}

// ---------------- stage B: BN params + merged weight table ----------------
__global__ void prep_kernel(const float* __restrict__ gamma, const float* __restrict__ beta,
                            const float* __restrict__ alphas, float* __restrict__ ws) {
  int t = threadIdx.x;
  if (t < NCH) {
    float s = 0.f, q = 0.f;
    for (int b = 0; b < NB; ++b) {
      s += ws[WS_PSUM + b * NCH + t];
      q += ws[WS_PSQ  + b * NCH + t];
    }
    const float inv = 1.0f / ((float)NB * PLANE);
    float mean = s * inv;
    float var  = q * inv - mean * mean;
    float sc = gamma[t] * rsqrtf(var + 1e-5f);
    ws[WS_SCALE + t] = sc;
    ws[WS_SHIFT + t] = beta[t] - mean * sc;
  }
  if (t == 0) {
    float w[14][7];
    for (int r = 0; r < 14; ++r) {
      float m = -1e30f;
      for (int k = 0; k < 7; ++k) m = fmaxf(m, alphas[r * 7 + k]);
      float sum = 0.f;
      for (int k = 0; k < 7; ++k) { float e = expf(alphas[r * 7 + k] - m); w[r][k] = e; sum += e; }
      float is = 1.0f / sum;
      for (int k = 0; k < 7; ++k) w[r][k] *= is;
    }
    for (int i = 0; i < 96; ++i) ws[WS_TAB + i] = 0.f;
    for (int i = 0; i < 4;  ++i) ws[WS_CONST + i] = 0.f;
    const int map[14][2] = {
      {0,0},{0,0},
      {0,1},{0,1},{1,1},
      {0,2},{0,2},{1,2},{2,2},
      {0,3},{0,3},{1,3},{2,3},{3,3}
    };
    for (int r = 0; r < 14; ++r) {
      int p = map[r][0], tg = map[r][1];
      float* cf = ws + WS_TAB + (p * 4 + tg) * 6;
      cf[0] += w[r][0] - w[r][2];       // identity
      cf[1] += w[r][1] * (1.0f / 9.0f); // blur (/9 folded)
      cf[2] += w[r][3];                 // fliplr
      cf[3] += w[r][4];                 // flipud
      cf[4] += w[r][5];                 // roll(+4,+4)
      cf[5] += w[r][6];                 // rot90
      ws[WS_CONST + tg] += w[r][2];     // constant w2
    }
  }
}

// ---------------- main fused kernel ----------------
// R16 structure + RACE-FREE fp16 s4-partials. R17 post-mortem: fp32 finals
// for plane P overlap the fp16 partial slots of OTHER threads in the same
// region (fp32 row r covers partial rows 2r..2r+7) -> W-after-R race -> NaN.
// Fix: the s4-final loop does NO global writes (consume partial, stash
// result to LDS only); the fp32 plane-2 writeback moves past the barrier.
// s5 partials stay fp32 (same-thread RMW over identical rows = safe).

__device__ __forceinline__ float ldshw(const h2* L, int i, int j) {
  int s = ((j >> 2) & 31) ^ (i >> 2);
  h2 p = L[(i << 6) + (s << 1) + ((j & 2) >> 1)];
  return (j & 1) ? (float)p.y : (float)p.x;
}

#define RDQ(L, I, B, M) {                                                      \
  int s_ = (B) ^ ((I) >> 2);                                                   \
  h4 pp_ = *(const h4*)((L) + (((I) << 6) + (s_ << 1)));                       \
  M.x = (float)pp_.x; M.y = (float)pp_.y;                                      \
  M.z = (float)pp_.z; M.w = (float)pp_.w; }

#define WRQ(L, I, B, VV) {                                                     \
  int s_ = (B) ^ ((I) >> 2);                                                   \
  h4 pp_;                                                                      \
  pp_.x = (_Float16)VV.x; pp_.y = (_Float16)VV.y;                              \
  pp_.z = (_Float16)VV.z; pp_.w = (_Float16)VV.w;                              \
  *(h4*)((L) + (((I) << 6) + (s_ << 1))) = pp_; }

#define HROW(h, m, lo, hi)                                                     \
  h.x = lo + m.x + m.y; h.y = m.x + m.y + m.z;                                 \
  h.z = m.y + m.z + m.w; h.w = m.z + m.w + hi;

#define FMA4(T, C, M)                                                          \
  T.x += (C) * M.x; T.y += (C) * M.y; T.z += (C) * M.z; T.w += (C) * M.w;

#define BLUR4(T, A, B, Cq)                                                     \
  T.x += c1 * (A.x + B.x + Cq.x); T.y += c1 * (A.y + B.y + Cq.y);              \
  T.z += c1 * (A.z + B.z + Cq.z); T.w += c1 * (A.w + B.w + Cq.w);

#define FLIPL(T, M)                                                            \
  T.x += c2 * M.w; T.y += c2 * M.z; T.z += c2 * M.y; T.w += c2 * M.x;

#define GATHER(L, OI, TYC) {                                                   \
  float4 m, hA, hB, hC; float lo, hi; int ri;                                  \
  ri = ((OI) == 0) ? 1 : (OI) - 1;                                             \
  RDQ(L, ri, tx, m) lo = ldshw(L, ri, cLo); hi = ldshw(L, ri, cHi);            \
  HROW(hA, m, lo, hi)                                                          \
  RDQ(L, (OI), tx, m) lo = ldshw(L, (OI), cLo); hi = ldshw(L, (OI), cHi);      \
  FMA4(T0, c0, m)                                                              \
  HROW(hB, m, lo, hi)                                                          \
  RDQ(L, (OI)+1, tx, m) lo = ldshw(L, (OI)+1, cLo); hi = ldshw(L, (OI)+1, cHi);\
  FMA4(T1, c0, m)                                                              \
  HROW(hC, m, lo, hi)                                                          \
  BLUR4(T0, hA, hB, hC)                                                        \
  RDQ(L, (OI)+2, tx, m) lo = ldshw(L, (OI)+2, cLo); hi = ldshw(L, (OI)+2, cHi);\
  FMA4(T2, c0, m)                                                              \
  HROW(hA, m, lo, hi)                                                          \
  BLUR4(T1, hB, hC, hA)                                                        \
  RDQ(L, (OI)+3, tx, m) lo = ldshw(L, (OI)+3, cLo); hi = ldshw(L, (OI)+3, cHi);\
  FMA4(T3, c0, m)                                                              \
  HROW(hB, m, lo, hi)                                                          \
  BLUR4(T2, hC, hA, hB)                                                        \
  ri = ((OI) == 124) ? 126 : (OI) + 4;                                         \
  RDQ(L, ri, tx, m) lo = ldshw(L, ri, cLo); hi = ldshw(L, ri, cHi);            \
  HROW(hC, m, lo, hi)                                                          \
  BLUR4(T3, hA, hB, hC)                                                        \
  /* fliplr */                                                                 \
  RDQ(L, (OI),   31 - tx, m) FLIPL(T0, m)                                      \
  RDQ(L, (OI)+1, 31 - tx, m) FLIPL(T1, m)                                      \
  RDQ(L, (OI)+2, 31 - tx, m) FLIPL(T2, m)                                      \
  RDQ(L, (OI)+3, 31 - tx, m) FLIPL(T3, m)                                      \
  /* flipud */                                                                 \
  RDQ(L, 127 - (OI), tx, m) FMA4(T0, c3, m)                                    \
  RDQ(L, 126 - (OI), tx, m) FMA4(T1, c3, m)                                    \
  RDQ(L, 125 - (OI), tx, m) FMA4(T2, c3, m)                                    \
  RDQ(L, 124 - (OI), tx, m) FMA4(T3, c3, m)                                    \
  /* roll(+4,+4) */                                                            \
  RDQ(L, ((OI) - 4) & 127, rc, m) FMA4(T0, c4, m)                              \
  RDQ(L, ((OI) - 3) & 127, rc, m) FMA4(T1, c4, m)                              \
  RDQ(L, ((OI) - 2) & 127, rc, m) FMA4(T2, c4, m)                              \
  RDQ(L, ((OI) - 1) & 127, rc, m) FMA4(T3, c4, m)                              \
  /* rot90 k=1: out[i][j] = src[j][127-i] */                                   \
  RDQ(L, oj,     31 - (TYC), m)                                                \
  T0.x += c5 * m.w; T1.x += c5 * m.z; T2.x += c5 * m.y; T3.x += c5 * m.x;      \
  RDQ(L, oj + 1, 31 - (TYC), m)                                                \
  T0.y += c5 * m.w; T1.y += c5 * m.z; T2.y += c5 * m.y; T3.y += c5 * m.x;      \
  RDQ(L, oj + 2, 31 - (TYC), m)                                                \
  T0.z += c5 * m.w; T1.z += c5 * m.z; T2.z += c5 * m.y; T3.z += c5 * m.x;      \
  RDQ(L, oj + 3, 31 - (TYC), m)                                                \
  T0.w += c5 * m.w; T1.w += c5 * m.z; T2.w += c5 * m.y; T3.w += c5 * m.x;      \
}

#define LDCF(P, TG) {                                                          \
  const float* cfp = wsf + WS_TAB + ((P) * 4 + (TG)) * 6;                      \
  c0 = cfp[0]; c1 = cfp[1]; c2 = cfp[2]; c3 = cfp[3]; c4 = cfp[4]; c5 = cfp[5]; }

#define SETC(K) {                                                              \
  float cst = wsf[WS_CONST + (K)];                                             \
  T0.x = cst; T0.y = cst; T0.z = cst; T0.w = cst; T1 = T0; T2 = T0; T3 = T0; }

#define STAGE_BN(L, OI) {                                                      \
  float4 v;                                                                    \
  v = x4[((OI)+0)*32 + tx]; v.x = v.x*sc+sh; v.y = v.y*sc+sh; v.z = v.z*sc+sh; \
  v.w = v.w*sc+sh; WRQ(L, (OI)+0, tx, v)                                       \
  v = x4[((OI)+1)*32 + tx]; v.x = v.x*sc+sh; v.y = v.y*sc+sh; v.z = v.z*sc+sh; \
  v.w = v.w*sc+sh; WRQ(L, (OI)+1, tx, v)                                       \
  v = x4[((OI)+2)*32 + tx]; v.x = v.x*sc+sh; v.y = v.y*sc+sh; v.z = v.z*sc+sh; \
  v.w = v.w*sc+sh; WRQ(L, (OI)+2, tx, v)                                       \
  v = x4[((OI)+3)*32 + tx]; v.x = v.x*sc+sh; v.y = v.y*sc+sh; v.z = v.z*sc+sh; \
  v.w = v.w*sc+sh; WRQ(L, (OI)+3, tx, v) }

#define STAGE_OUT(L, TG, OI) {                                                 \
  float4 v;                                                                    \
  v = out4[(pbase + (TG)*NCH)*4096 + ((OI)+0)*32 + tx]; WRQ(L, (OI)+0, tx, v)  \
  v = out4[(pbase + (TG)*NCH)*4096 + ((OI)+1)*32 + tx]; WRQ(L, (OI)+1, tx, v)  \
  v = out4[(pbase + (TG)*NCH)*4096 + ((OI)+2)*32 + tx]; WRQ(L, (OI)+2, tx, v)  \
  v = out4[(pbase + (TG)*NCH)*4096 + ((OI)+3)*32 + tx]; WRQ(L, (OI)+3, tx, v) }

#define WRITEV(TG, OI) {                                                       \
  out4[(pbase + (TG)*NCH)*4096 + ((OI)+0)*32 + tx] = T0;                       \
  out4[(pbase + (TG)*NCH)*4096 + ((OI)+1)*32 + tx] = T1;                       \
  out4[(pbase + (TG)*NCH)*4096 + ((OI)+2)*32 + tx] = T2;                       \
  out4[(pbase + (TG)*NCH)*4096 + ((OI)+3)*32 + tx] = T3; }

#define LOADV(TG, OI) {                                                        \
  T0 = out4[(pbase + (TG)*NCH)*4096 + ((OI)+0)*32 + tx];                       \
  T1 = out4[(pbase + (TG)*NCH)*4096 + ((OI)+1)*32 + tx];                       \
  T2 = out4[(pbase + (TG)*NCH)*4096 + ((OI)+2)*32 + tx];                       \
  T3 = out4[(pbase + (TG)*NCH)*4096 + ((OI)+3)*32 + tx]; }

// fp16-packed partial (plane TG first half): row r -> h4 slot r*32+tx,
// 8B/lane coalesced. Same-thread write->read only.
#define PWRITEV(TG, OI) {                                                      \
  h4* ph_ = (h4*)(outh + ((pbase + (TG)*NCH) << 15));                          \
  h4 pp_;                                                                      \
  pp_.x = (_Float16)T0.x; pp_.y = (_Float16)T0.y;                              \
  pp_.z = (_Float16)T0.z; pp_.w = (_Float16)T0.w;                              \
  ph_[((OI)+0)*32 + tx] = pp_;                                                 \
  pp_.x = (_Float16)T1.x; pp_.y = (_Float16)T1.y;                              \
  pp_.z = (_Float16)T1.z; pp_.w = (_Float16)T1.w;                              \
  ph_[((OI)+1)*32 + tx] = pp_;                                                 \
  pp_.x = (_Float16)T2.x; pp_.y = (_Float16)T2.y;                              \
  pp_.z = (_Float16)T2.z; pp_.w = (_Float16)T2.w;                              \
  ph_[((OI)+2)*32 + tx] = pp_;                                                 \
  pp_.x = (_Float16)T3.x; pp_.y = (_Float16)T3.y;                              \
  pp_.z = (_Float16)T3.z; pp_.w = (_Float16)T3.w;                              \
  ph_[((OI)+3)*32 + tx] = pp_; }

#define PLOADV(TG, OI) {                                                       \
  const h4* ph_ = (const h4*)(outh + ((pbase + (TG)*NCH) << 15));              \
  h4 pp_;                                                                      \
  pp_ = ph_[((OI)+0)*32 + tx];                                                 \
  T0.x = (float)pp_.x; T0.y = (float)pp_.y;                                    \
  T0.z = (float)pp_.z; T0.w = (float)pp_.w;                                    \
  pp_ = ph_[((OI)+1)*32 + tx];                                                 \
  T1.x = (float)pp_.x; T1.y = (float)pp_.y;                                    \
  T1.z = (float)pp_.z; T1.w = (float)pp_.w;                                    \
  pp_ = ph_[((OI)+2)*32 + tx];                                                 \
  T2.x = (float)pp_.x; T2.y = (float)pp_.y;                                    \
  T2.z = (float)pp_.z; T2.w = (float)pp_.w;                                    \
  pp_ = ph_[((OI)+3)*32 + tx];                                                 \
  T3.x = (float)pp_.x; T3.y = (float)pp_.y;                                    \
  T3.z = (float)pp_.z; T3.w = (float)pp_.w; }

#define STASHV(L, OI) {                                                        \
  WRQ(L, (OI)+0, tx, T0) WRQ(L, (OI)+1, tx, T1)                                \
  WRQ(L, (OI)+2, tx, T2) WRQ(L, (OI)+3, tx, T3) }

__global__ __launch_bounds__(256, 1)
void main_kernel(const float* __restrict__ x,
                 const float* __restrict__ wsf, float* out)
{
  __shared__ h2 lds[2 * 8192];            // 64 KB total -> 2 blocks/CU
  h2* h0 = lds;
  h2* h1 = lds + 8192;
  int bx = blockIdx.x;
  int b = bx / NCH, c = bx % NCH;
  int tid = threadIdx.x;
  int ty = tid >> 5, tx = tid & 31;       // ty in 0..7
  int oj = tx << 2;
  int cLo = (tx == 0)  ? 1   : oj - 1;
  int cHi = (tx == 31) ? 126 : oj + 4;
  int rc  = (tx + 31) & 31;
  float4* out4 = (float4*)out;
  _Float16* outh = (_Float16*)out;
  const size_t pbase = (size_t)b * 192 + c;
  const float4* x4 = (const float4*)x + (size_t)bx * 4096;
  float sc = wsf[WS_SCALE + c], sh = wsf[WS_SHIFT + c];

  float4 T0, T1, T2, T3;
  float c0, c1, c2, c3, c4, c5;

  // stage s -> buf0
  #pragma unroll 1
  for (int k = 0; k < 4; ++k) {
    int oi = (ty + 8 * k) << 2;
    STAGE_BN(h0, oi);
  }
  __syncthreads();

  // s2 = L(0,0)[s]; stash s2 -> buf1
  #pragma unroll 1
  for (int k = 0; k < 4; ++k) {
    int oi = (ty + 8 * k) << 2; int tyc = ty + 8 * k;
    SETC(0); LDCF(0, 0);
    GATHER(h0, oi, tyc);
    WRITEV(0, oi);
    STASHV(h1, oi);
  }
  __syncthreads();

  // s3 full (fp32); s4 partial (fp16-packed); s5 partial (fp32, safe RMW)
  #pragma unroll 1
  for (int k = 0; k < 4; ++k) {
    int oi = (ty + 8 * k) << 2; int tyc = ty + 8 * k;
    SETC(1); LDCF(0, 1); GATHER(h0, oi, tyc);
             LDCF(1, 1); GATHER(h1, oi, tyc);
    WRITEV(1, oi);
    SETC(2); LDCF(0, 2); GATHER(h0, oi, tyc);
             LDCF(1, 2); GATHER(h1, oi, tyc);
    PWRITEV(2, oi);                         // partial s4, fp16 (intermediates)
    SETC(3); LDCF(0, 3); GATHER(h0, oi, tyc);
             LDCF(1, 3); GATHER(h1, oi, tyc);
    WRITEV(3, oi);                          // partial s5, fp32
  }
  __syncthreads();                          // all buf0 reads done; s3 visible

  // restage s3 -> buf0
  #pragma unroll 1
  for (int k = 0; k < 4; ++k) {
    int oi = (ty + 8 * k) << 2;
    STAGE_OUT(h0, 1, oi);
  }
  __syncthreads();

  // s4 final: consume fp16 partial + L(2,2)[s3]; stash to buf1 — NO global
  // writes here (plane-2 fp32 writeback is deferred past the barrier so no
  // thread can clobber another's unread fp16 partial).
  #pragma unroll 1
  for (int k = 0; k < 4; ++k) {
    int oi = (ty + 8 * k) << 2; int tyc = ty + 8 * k;
    PLOADV(2, oi); LDCF(2, 2); GATHER(h0, oi, tyc);
    STASHV(h1, oi);
  }
  __syncthreads();                          // partials consumed; s4 in buf1

  // s5 final (+ deferred plane-2 fp32 writeback from buf1)
  #pragma unroll 1
  for (int k = 0; k < 4; ++k) {
    int oi = (ty + 8 * k) << 2; int tyc = ty + 8 * k;
    // writeback s4 (own rows, read from LDS stash)
    {
      float4 f;
      RDQ(h1, oi + 0, tx, f) out4[(pbase + 2*NCH)*4096 + (oi+0)*32 + tx] = f;
      RDQ(h1, oi + 1, tx, f) out4[(pbase + 2*NCH)*4096 + (oi+1)*32 + tx] = f;
      RDQ(h1, oi + 2, tx, f) out4[(pbase + 2*NCH)*4096 + (oi+2)*32 + tx] = f;
      RDQ(h1, oi + 3, tx, f) out4[(pbase + 2*NCH)*4096 + (oi+3)*32 + tx] = f;
    }
    LOADV(3, oi);
    LDCF(2, 3); GATHER(h0, oi, tyc);
    LDCF(3, 3); GATHER(h1, oi, tyc);
    WRITEV(3, oi);
  }
}

extern "C" void kernel_launch(void* const* d_in, const int* in_sizes, int n_in,
                              void* d_out, int out_size, void* d_ws, size_t ws_size,
                              hipStream_t stream) {
  (void)in_sizes; (void)n_in; (void)out_size; (void)ws_size;
  const float* x     = (const float*)d_in[0];
  const float* gamma = (const float*)d_in[1];
  const float* beta  = (const float*)d_in[2];
  const float* a_red = (const float*)d_in[4];   // reference uses alphas_reduce
  float* ws  = (float*)d_ws;
  float* out = (float*)d_out;

  stats_kernel<<<NPLANES, 256, 0, stream>>>(x, ws);
  prep_kernel<<<1, 64, 0, stream>>>(gamma, beta, a_red, ws);
  main_kernel<<<NPLANES, 256, 0, stream>>>(x, ws, out);
}